// Round 8
// baseline (77.833 us; speedup 1.0000x reference)
//
#include <hip/hip_runtime.h>
#include <math.h>

#define DIM 160
#define SL4 (DIM * DIM / 4)    // 6400 float4 per d-slice
#define CD 10                  // d-slices per blur_wd thread
#define CHH 10                 // h-rows per blur_h thread
#define DPB 8                  // d-slices per blur_h block (8*40 = 320 thr)

struct W7 { float w[7]; };

__device__ __forceinline__ void fma4(float4& a, float w, const float4& v) {
    a.x += w * v.x; a.y += w * v.y; a.z += w * v.z; a.w += w * v.w;
}

// ---- K1: fused W+D, register d-march (blur_dm structure + in-reg W): x -> ws
__global__ __launch_bounds__(256) void blur_wd(const float4* __restrict__ in,
                                               float4* __restrict__ out, W7 wt) {
    const int sblocks = SL4 / 256;            // 25
    const int ndc = DIM / CD;                 // 16
    int b    = blockIdx.x;
    int sblk = b % sblocks;
    int dc   = (b / sblocks) % ndc;
    int nc   = b / (sblocks * ndc);
    int s4   = sblk * 256 + threadIdx.x;      // (h,c) position in slice
    int c    = s4 % 40;
    int d0   = dc * CD;

    const float4* src = in  + (size_t)nc * DIM * SL4;
    float4*       dst = out + (size_t)nc * DIM * SL4;

    const float4 z4 = make_float4(0.f, 0.f, 0.f, 0.f);
    const bool cl = (c >= 1), cr = (c <= 38);
    const float w0 = wt.w[0], w1 = wt.w[1], w2 = wt.w[2], w3 = wt.w[3],
                w4 = wt.w[4], w5 = wt.w[5], w6 = wt.w[6];

    // W-blur one row-segment of slice dd, fully in registers
    auto wtap = [&](int dd) -> float4 {
        const float4* p = src + (size_t)dd * SL4 + s4;
        float4 l = cl ? p[-1] : z4;
        float4 m = p[0];
        float4 r = cr ? p[1] : z4;
        float f1 = l.y, f2 = l.z, f3 = l.w;
        float f4_ = m.x, f5 = m.y, f6 = m.z, f7 = m.w;
        float f8 = r.x, f9 = r.y, f10 = r.z;
        float4 o;
        o.x = w0*f1 + w1*f2 + w2*f3 + w3*f4_ + w4*f5 + w5*f6 + w6*f7;
        o.y = w0*f2 + w1*f3 + w2*f4_ + w3*f5 + w4*f6 + w5*f7 + w6*f8;
        o.z = w0*f3 + w1*f4_ + w2*f5 + w3*f6 + w4*f7 + w5*f8 + w6*f9;
        o.w = w0*f4_ + w1*f5 + w2*f6 + w3*f7 + w4*f8 + w5*f9 + w6*f10;
        return o;
    };

    float4 ring[7];
#pragma unroll
    for (int j = 0; j < 6; ++j) {             // prologue: slices d0-3 .. d0+2
        int dd = d0 - 3 + j;                  // block-uniform guard
        ring[j] = (dd >= 0) ? wtap(dd) : z4;
    }
#pragma unroll
    for (int k = 0; k < CD; ++k) {
        int dd = d0 + 3 + k;                  // block-uniform guard
        ring[(k + 6) % 7] = (dd < DIM) ? wtap(dd) : z4;
        float4 o = z4;
#pragma unroll
        for (int j = 0; j < 7; ++j)
            fma4(o, wt.w[j], ring[(k + j) % 7]);
        dst[(size_t)(d0 + k) * SL4 + s4] = o;
    }
}

// ---- K2: H blur, register h-march (blur_dm with stride 40): ws -> out ----
__global__ __launch_bounds__(320) void blur_h(const float4* __restrict__ in,
                                              float4* __restrict__ out, W7 wt) {
    const int dgroups = DIM / DPB;            // 20
    const int nhc = DIM / CHH;                // 16
    int b  = blockIdx.x;
    int hc = b % nhc;
    int dg = (b / nhc) % dgroups;
    int nc = b / (nhc * dgroups);
    int c  = threadIdx.x % 40;
    int dl = threadIdx.x / 40;
    int d  = dg * DPB + dl;
    int h0 = hc * CHH;

    const float4* sl  = in  + ((size_t)nc * DIM + d) * SL4;
    float4*       osl = out + ((size_t)nc * DIM + d) * SL4;

    const float4 z4 = make_float4(0.f, 0.f, 0.f, 0.f);
    float4 ring[7];
#pragma unroll
    for (int j = 0; j < 6; ++j) {             // prologue: rows h0-3 .. h0+2
        int hh = h0 - 3 + j;                  // block-uniform guard
        ring[j] = (hh >= 0) ? sl[hh * 40 + c] : z4;
    }
#pragma unroll
    for (int k = 0; k < CHH; ++k) {
        int hh = h0 + 3 + k;                  // block-uniform guard
        ring[(k + 6) % 7] = (hh < DIM) ? sl[hh * 40 + c] : z4;
        float4 o = z4;
#pragma unroll
        for (int j = 0; j < 7; ++j)
            fma4(o, wt.w[j], ring[(k + j) % 7]);
        osl[(h0 + k) * 40 + c] = o;
    }
}

// ---- Fallback: direct 343-tap (only if ws too small) ----
__global__ void blur3d_naive(const float* __restrict__ in, float* __restrict__ out,
                             W7 wt, int total) {
    int idx = blockIdx.x * blockDim.x + threadIdx.x;
    if (idx >= total) return;
    int w = idx % DIM;
    int h = (idx / DIM) % DIM;
    int d = (idx / (DIM * DIM)) % DIM;
    const float* base = in + (idx - w - h * DIM - d * DIM * DIM);
    float acc = 0.f;
    for (int a = 0; a < 7; ++a) {
        int dd = d + a - 3;
        if (dd < 0 || dd >= DIM) continue;
        for (int bb = 0; bb < 7; ++bb) {
            int hh = h + bb - 3;
            if (hh < 0 || hh >= DIM) continue;
            float wab = wt.w[a] * wt.w[bb];
            for (int cx = 0; cx < 7; ++cx) {
                int ww = w + cx - 3;
                if (ww < 0 || ww >= DIM) continue;
                acc += wab * wt.w[cx] * base[(dd * DIM + hh) * DIM + ww];
            }
        }
    }
    out[idx] = acc;
}

extern "C" void kernel_launch(void* const* d_in, const int* in_sizes, int n_in,
                              void* d_out, int out_size, void* d_ws, size_t ws_size,
                              hipStream_t stream) {
    const float* x = (const float*)d_in[0];
    float* out = (float*)d_out;
    const int total = out_size;               // 2*2*160^3

    W7 wt;
    double s = 0.0;
    for (int i = 0; i < 7; ++i) {
        double v = exp(-((i - 3) * (i - 3)) / 8.0);
        wt.w[i] = (float)v;
        s += v;
    }
    for (int i = 0; i < 7; ++i) wt.w[i] = (float)(wt.w[i] / s);

    if (ws_size >= (size_t)total * sizeof(float)) {
        float* tmp = (float*)d_ws;
        const int nc = total / (DIM * DIM * DIM);             // 4
        const int gridWD = nc * (DIM / CD) * (SL4 / 256);     // 4*16*25 = 1600
        blur_wd<<<gridWD, 256, 0, stream>>>(
            (const float4*)x, (float4*)tmp, wt);
        const int gridH = nc * (DIM / DPB) * (DIM / CHH);     // 4*20*16 = 1280
        blur_h<<<gridH, 320, 0, stream>>>(
            (const float4*)tmp, (float4*)out, wt);
    } else {
        blur3d_naive<<<(total + 255) / 256, 256, 0, stream>>>(x, out, wt, total);
    }
}

// Round 9
// 59.662 us; speedup vs baseline: 1.3046x; 1.3046x over previous
//
#include <hip/hip_runtime.h>
#include <math.h>

#define DIM 160
#define SL4 (DIM * DIM / 4)    // 6400 float4 per d-slice
#define CD 10                  // d-slices per blur_wd thread
#define CHH 10                 // h-rows per blur_h thread
#define DPB 8                  // d-slices per blur_h block (8*40 = 320 thr)

struct W7 { float w[7]; };

__device__ __forceinline__ void fma4(float4& a, float w, const float4& v) {
    a.x += w * v.x; a.y += w * v.y; a.z += w * v.z; a.w += w * v.w;
}

// ---- K1: fused W+D, register d-march; W-neighbors via wave shuffles ----
__global__ __launch_bounds__(256) void blur_wd(const float4* __restrict__ in,
                                               float4* __restrict__ out, W7 wt) {
    const int sblocks = SL4 / 256;            // 25
    const int ndc = DIM / CD;                 // 16
    int b    = blockIdx.x;
    int sblk = b % sblocks;
    int dc   = (b / sblocks) % ndc;
    int nc   = b / (sblocks * ndc);
    int s4   = sblk * 256 + threadIdx.x;      // (h,c) position in slice
    int c    = s4 % 40;
    int d0   = dc * CD;
    const int lane = threadIdx.x & 63;

    const float4* src = in  + (size_t)nc * DIM * SL4;
    float4*       dst = out + (size_t)nc * DIM * SL4;

    const float4 z4 = make_float4(0.f, 0.f, 0.f, 0.f);
    const bool cl  = (c >= 1), cr = (c <= 38);
    const bool eL  = (lane == 0) && cl;       // needs cross-wave left load
    const bool eR  = (lane == 63) && cr;      // needs cross-wave right load
    const float w0 = wt.w[0], w1 = wt.w[1], w2 = wt.w[2], w3 = wt.w[3],
                w4 = wt.w[4], w5 = wt.w[5], w6 = wt.w[6];

    // W-blur one float4 of slice dd: 1 full load + 6 shuffles (+ edge loads)
    auto wtap = [&](int dd) -> float4 {
        const float4* p = src + (size_t)dd * SL4 + s4;
        float4 m = p[0];
        float ly = __shfl_up(m.y, 1);
        float lz = __shfl_up(m.z, 1);
        float lw = __shfl_up(m.w, 1);
        float rx = __shfl_down(m.x, 1);
        float ry = __shfl_down(m.y, 1);
        float rz = __shfl_down(m.z, 1);
        if (eL) { float4 l = p[-1]; ly = l.y; lz = l.z; lw = l.w; }
        if (eR) { float4 r = p[1];  rx = r.x; ry = r.y; rz = r.z; }
        if (!cl) { ly = 0.f; lz = 0.f; lw = 0.f; }    // w zero-pad
        if (!cr) { rx = 0.f; ry = 0.f; rz = 0.f; }
        float4 o;
        o.x = w0*ly  + w1*lz  + w2*lw  + w3*m.x + w4*m.y + w5*m.z + w6*m.w;
        o.y = w0*lz  + w1*lw  + w2*m.x + w3*m.y + w4*m.z + w5*m.w + w6*rx;
        o.z = w0*lw  + w1*m.x + w2*m.y + w3*m.z + w4*m.w + w5*rx  + w6*ry;
        o.w = w0*m.x + w1*m.y + w2*m.z + w3*m.w + w4*rx  + w5*ry  + w6*rz;
        return o;
    };

    float4 ring[7];
#pragma unroll
    for (int j = 0; j < 6; ++j) {             // prologue: slices d0-3 .. d0+2
        int dd = d0 - 3 + j;                  // block-uniform guard
        ring[j] = (dd >= 0) ? wtap(dd) : z4;
    }
#pragma unroll
    for (int k = 0; k < CD; ++k) {
        int dd = d0 + 3 + k;                  // block-uniform guard
        ring[(k + 6) % 7] = (dd < DIM) ? wtap(dd) : z4;
        float4 o = z4;
#pragma unroll
        for (int j = 0; j < 7; ++j)
            fma4(o, wt.w[j], ring[(k + j) % 7]);
        dst[(size_t)(d0 + k) * SL4 + s4] = o;
    }
}

// ---- K2: H blur, register h-march (proven ~19 us): ws -> out ----
__global__ __launch_bounds__(320) void blur_h(const float4* __restrict__ in,
                                              float4* __restrict__ out, W7 wt) {
    const int dgroups = DIM / DPB;            // 20
    const int nhc = DIM / CHH;                // 16
    int b  = blockIdx.x;
    int hc = b % nhc;
    int dg = (b / nhc) % dgroups;
    int nc = b / (nhc * dgroups);
    int c  = threadIdx.x % 40;
    int dl = threadIdx.x / 40;
    int d  = dg * DPB + dl;
    int h0 = hc * CHH;

    const float4* sl  = in  + ((size_t)nc * DIM + d) * SL4;
    float4*       osl = out + ((size_t)nc * DIM + d) * SL4;

    const float4 z4 = make_float4(0.f, 0.f, 0.f, 0.f);
    float4 ring[7];
#pragma unroll
    for (int j = 0; j < 6; ++j) {             // prologue: rows h0-3 .. h0+2
        int hh = h0 - 3 + j;                  // block-uniform guard
        ring[j] = (hh >= 0) ? sl[hh * 40 + c] : z4;
    }
#pragma unroll
    for (int k = 0; k < CHH; ++k) {
        int hh = h0 + 3 + k;                  // block-uniform guard
        ring[(k + 6) % 7] = (hh < DIM) ? sl[hh * 40 + c] : z4;
        float4 o = z4;
#pragma unroll
        for (int j = 0; j < 7; ++j)
            fma4(o, wt.w[j], ring[(k + j) % 7]);
        osl[(h0 + k) * 40 + c] = o;
    }
}

// ---- Fallback: direct 343-tap (only if ws too small) ----
__global__ void blur3d_naive(const float* __restrict__ in, float* __restrict__ out,
                             W7 wt, int total) {
    int idx = blockIdx.x * blockDim.x + threadIdx.x;
    if (idx >= total) return;
    int w = idx % DIM;
    int h = (idx / DIM) % DIM;
    int d = (idx / (DIM * DIM)) % DIM;
    const float* base = in + (idx - w - h * DIM - d * DIM * DIM);
    float acc = 0.f;
    for (int a = 0; a < 7; ++a) {
        int dd = d + a - 3;
        if (dd < 0 || dd >= DIM) continue;
        for (int bb = 0; bb < 7; ++bb) {
            int hh = h + bb - 3;
            if (hh < 0 || hh >= DIM) continue;
            float wab = wt.w[a] * wt.w[bb];
            for (int cx = 0; cx < 7; ++cx) {
                int ww = w + cx - 3;
                if (ww < 0 || ww >= DIM) continue;
                acc += wab * wt.w[cx] * base[(dd * DIM + hh) * DIM + ww];
            }
        }
    }
    out[idx] = acc;
}

extern "C" void kernel_launch(void* const* d_in, const int* in_sizes, int n_in,
                              void* d_out, int out_size, void* d_ws, size_t ws_size,
                              hipStream_t stream) {
    const float* x = (const float*)d_in[0];
    float* out = (float*)d_out;
    const int total = out_size;               // 2*2*160^3

    W7 wt;
    double s = 0.0;
    for (int i = 0; i < 7; ++i) {
        double v = exp(-((i - 3) * (i - 3)) / 8.0);
        wt.w[i] = (float)v;
        s += v;
    }
    for (int i = 0; i < 7; ++i) wt.w[i] = (float)(wt.w[i] / s);

    if (ws_size >= (size_t)total * sizeof(float)) {
        float* tmp = (float*)d_ws;
        const int nc = total / (DIM * DIM * DIM);             // 4
        const int gridWD = nc * (DIM / CD) * (SL4 / 256);     // 4*16*25 = 1600
        blur_wd<<<gridWD, 256, 0, stream>>>(
            (const float4*)x, (float4*)tmp, wt);
        const int gridH = nc * (DIM / DPB) * (DIM / CHH);     // 4*20*16 = 1280
        blur_h<<<gridH, 320, 0, stream>>>(
            (const float4*)tmp, (float4*)out, wt);
    } else {
        blur3d_naive<<<(total + 255) / 256, 256, 0, stream>>>(x, out, wt, total);
    }
}

// Round 10
// 57.945 us; speedup vs baseline: 1.3432x; 1.0296x over previous
//
#include <hip/hip_runtime.h>
#include <math.h>

#define DIM 160
#define SL4 (DIM * DIM / 4)    // 6400 float4 per d-slice
#define CD 10                  // d-slices per blur_wd thread
#define NSTEP (CD + 6)         // 16 pipeline steps
#define CHH 10                 // h-rows per blur_h thread
#define DPB 8                  // d-slices per blur_h block (8*40 = 320 thr)

struct W7 { float w[7]; };

__device__ __forceinline__ void fma4(float4& a, float w, const float4& v) {
    a.x += w * v.x; a.y += w * v.y; a.z += w * v.z; a.w += w * v.w;
}

// ---- K1: fused W+D d-march, shuffle W-neighbors, 1-step load prefetch ----
__global__ __launch_bounds__(256) void blur_wd(const float4* __restrict__ in,
                                               float4* __restrict__ out, W7 wt) {
    const int sblocks = SL4 / 256;            // 25
    const int ndc = DIM / CD;                 // 16
    int b    = blockIdx.x;
    int sblk = b % sblocks;
    int dc   = (b / sblocks) % ndc;
    int nc   = b / (sblocks * ndc);
    int s4   = sblk * 256 + threadIdx.x;      // (h,c) position in slice
    int c    = s4 % 40;
    int d0   = dc * CD;
    const int lane = threadIdx.x & 63;

    const float4* src = in  + (size_t)nc * DIM * SL4;
    float4*       dst = out + (size_t)nc * DIM * SL4;

    const float4 z4 = make_float4(0.f, 0.f, 0.f, 0.f);
    const float3 z3 = make_float3(0.f, 0.f, 0.f);
    const bool cl  = (c >= 1), cr = (c <= 38);
    const bool eL  = (lane == 0) && cl;       // wave-edge: needs real left load
    const bool eR  = (lane == 63) && cr;      // wave-edge: needs real right load
    const float w0 = wt.w[0], w1 = wt.w[1], w2 = wt.w[2], w3 = wt.w[3],
                w4 = wt.w[4], w5 = wt.w[5], w6 = wt.w[6];

    // load stage for pipeline step jj (slice d0-3+jj), block-uniform guard
    auto ld = [&](int jj, float4& m, float3& l, float3& r) {
        int dd = d0 - 3 + jj;
        m = z4; l = z3; r = z3;
        if ((unsigned)dd < (unsigned)DIM) {
            const float4* p = src + (size_t)dd * SL4 + s4;
            m = p[0];
            if (eL) l = *(const float3*)((const float*)p - 3);
            if (eR) r = *(const float3*)((const float*)p + 4);
        }
    };
    // compute stage: W-blur from resident regs (6 shuffles, no loads)
    auto wcomb = [&](const float4& m, const float3& lv, const float3& rv) -> float4 {
        float ly = __shfl_up(m.y, 1);
        float lz = __shfl_up(m.z, 1);
        float lw = __shfl_up(m.w, 1);
        float rx = __shfl_down(m.x, 1);
        float ry = __shfl_down(m.y, 1);
        float rz = __shfl_down(m.z, 1);
        if (eL) { ly = lv.x; lz = lv.y; lw = lv.z; }
        if (eR) { rx = rv.x; ry = rv.y; rz = rv.z; }
        if (!cl) { ly = 0.f; lz = 0.f; lw = 0.f; }   // w zero-pad
        if (!cr) { rx = 0.f; ry = 0.f; rz = 0.f; }
        float4 o;
        o.x = w0*ly  + w1*lz  + w2*lw  + w3*m.x + w4*m.y + w5*m.z + w6*m.w;
        o.y = w0*lz  + w1*lw  + w2*m.x + w3*m.y + w4*m.z + w5*m.w + w6*rx;
        o.z = w0*lw  + w1*m.x + w2*m.y + w3*m.z + w4*m.w + w5*rx  + w6*ry;
        o.w = w0*m.x + w1*m.y + w2*m.z + w3*m.w + w4*rx  + w5*ry  + w6*rz;
        return o;
    };

    float4 ring[7];
    float4 mC, mN = z4;
    float3 lC, lN = z3, rC, rN = z3;

    ld(0, mC, lC, rC);                        // prime the pipeline
#pragma unroll
    for (int jj = 0; jj < NSTEP; ++jj) {
        if (jj < NSTEP - 1) ld(jj + 1, mN, lN, rN);   // prefetch next slice
        ring[jj % 7] = wcomb(mC, lC, rC);             // W-blur current slice
        if (jj >= 6) {                                // D-blur + store
            float4 o = z4;
#pragma unroll
            for (int j = 0; j < 7; ++j)
                fma4(o, wt.w[j], ring[(jj + 1 + j) % 7]);
            dst[(size_t)(d0 + jj - 6) * SL4 + s4] = o;
        }
        mC = mN; lC = lN; rC = rN;
    }
}

// ---- K2: H blur, register h-march (proven ~6 TB/s): ws -> out ----
__global__ __launch_bounds__(320) void blur_h(const float4* __restrict__ in,
                                              float4* __restrict__ out, W7 wt) {
    const int dgroups = DIM / DPB;            // 20
    const int nhc = DIM / CHH;                // 16
    int b  = blockIdx.x;
    int hc = b % nhc;
    int dg = (b / nhc) % dgroups;
    int nc = b / (nhc * dgroups);
    int c  = threadIdx.x % 40;
    int dl = threadIdx.x / 40;
    int d  = dg * DPB + dl;
    int h0 = hc * CHH;

    const float4* sl  = in  + ((size_t)nc * DIM + d) * SL4;
    float4*       osl = out + ((size_t)nc * DIM + d) * SL4;

    const float4 z4 = make_float4(0.f, 0.f, 0.f, 0.f);
    float4 ring[7];
#pragma unroll
    for (int j = 0; j < 6; ++j) {             // prologue: rows h0-3 .. h0+2
        int hh = h0 - 3 + j;                  // block-uniform guard
        ring[j] = (hh >= 0) ? sl[hh * 40 + c] : z4;
    }
#pragma unroll
    for (int k = 0; k < CHH; ++k) {
        int hh = h0 + 3 + k;                  // block-uniform guard
        ring[(k + 6) % 7] = (hh < DIM) ? sl[hh * 40 + c] : z4;
        float4 o = z4;
#pragma unroll
        for (int j = 0; j < 7; ++j)
            fma4(o, wt.w[j], ring[(k + j) % 7]);
        osl[(h0 + k) * 40 + c] = o;
    }
}

// ---- Fallback: direct 343-tap (only if ws too small) ----
__global__ void blur3d_naive(const float* __restrict__ in, float* __restrict__ out,
                             W7 wt, int total) {
    int idx = blockIdx.x * blockDim.x + threadIdx.x;
    if (idx >= total) return;
    int w = idx % DIM;
    int h = (idx / DIM) % DIM;
    int d = (idx / (DIM * DIM)) % DIM;
    const float* base = in + (idx - w - h * DIM - d * DIM * DIM);
    float acc = 0.f;
    for (int a = 0; a < 7; ++a) {
        int dd = d + a - 3;
        if (dd < 0 || dd >= DIM) continue;
        for (int bb = 0; bb < 7; ++bb) {
            int hh = h + bb - 3;
            if (hh < 0 || hh >= DIM) continue;
            float wab = wt.w[a] * wt.w[bb];
            for (int cx = 0; cx < 7; ++cx) {
                int ww = w + cx - 3;
                if (ww < 0 || ww >= DIM) continue;
                acc += wab * wt.w[cx] * base[(dd * DIM + hh) * DIM + ww];
            }
        }
    }
    out[idx] = acc;
}

extern "C" void kernel_launch(void* const* d_in, const int* in_sizes, int n_in,
                              void* d_out, int out_size, void* d_ws, size_t ws_size,
                              hipStream_t stream) {
    const float* x = (const float*)d_in[0];
    float* out = (float*)d_out;
    const int total = out_size;               // 2*2*160^3

    W7 wt;
    double s = 0.0;
    for (int i = 0; i < 7; ++i) {
        double v = exp(-((i - 3) * (i - 3)) / 8.0);
        wt.w[i] = (float)v;
        s += v;
    }
    for (int i = 0; i < 7; ++i) wt.w[i] = (float)(wt.w[i] / s);

    if (ws_size >= (size_t)total * sizeof(float)) {
        float* tmp = (float*)d_ws;
        const int nc = total / (DIM * DIM * DIM);             // 4
        const int gridWD = nc * (DIM / CD) * (SL4 / 256);     // 4*16*25 = 1600
        blur_wd<<<gridWD, 256, 0, stream>>>(
            (const float4*)x, (float4*)tmp, wt);
        const int gridH = nc * (DIM / DPB) * (DIM / CHH);     // 4*20*16 = 1280
        blur_h<<<gridH, 320, 0, stream>>>(
            (const float4*)tmp, (float4*)out, wt);
    } else {
        blur3d_naive<<<(total + 255) / 256, 256, 0, stream>>>(x, out, wt, total);
    }
}

// Round 11
// 57.243 us; speedup vs baseline: 1.3597x; 1.0123x over previous
//
#include <hip/hip_runtime.h>
#include <math.h>

#define DIM 160
#define SL4 (DIM * DIM / 4)    // 6400 float4 per d-slice
#define CD1 16                 // d-slices per blur_d thread
#define CHH 10                 // h-rows per blur_wh2 thread
#define NSTEPH (CHH + 6)       // 16 pipeline steps
#define DPB 8                  // d-slices per blur_wh2 block (8*40 = 320 thr)

struct W7 { float w[7]; };

__device__ __forceinline__ void fma4(float4& a, float w, const float4& v) {
    a.x += w * v.x; a.y += w * v.y; a.z += w * v.z; a.w += w * v.w;
}

// ---- K1: D blur, pure register d-march (cold input; proven structure) ----
__global__ __launch_bounds__(256) void blur_d(const float4* __restrict__ in,
                                              float4* __restrict__ out, W7 wt) {
    const int sblocks = SL4 / 256;            // 25
    const int ndc = DIM / CD1;                // 10
    int b    = blockIdx.x;
    int sblk = b % sblocks;
    int dc   = (b / sblocks) % ndc;
    int nc   = b / (sblocks * ndc);
    int s4   = sblk * 256 + threadIdx.x;
    int d0   = dc * CD1;
    const size_t base = (size_t)nc * DIM * SL4;

    const float4 z4 = make_float4(0.f, 0.f, 0.f, 0.f);
    float4 ring[7];
#pragma unroll
    for (int j = 0; j < 6; ++j) {             // prologue: slices d0-3 .. d0+2
        int dd = d0 - 3 + j;                  // block-uniform guard
        ring[j] = (dd >= 0) ? in[base + (size_t)dd * SL4 + s4] : z4;
    }
#pragma unroll
    for (int k = 0; k < CD1; ++k) {
        int dd = d0 + 3 + k;                  // block-uniform guard
        ring[(k + 6) % 7] = (dd < DIM) ? in[base + (size_t)dd * SL4 + s4] : z4;
        float4 o = z4;
#pragma unroll
        for (int j = 0; j < 7; ++j)
            fma4(o, wt.w[j], ring[(k + j) % 7]);
        out[base + (size_t)(d0 + k) * SL4 + s4] = o;
    }
}

// ---- K2: fused W+H h-march on L3-hot data; W via shuffles, pipelined ----
__global__ __launch_bounds__(320) void blur_wh2(const float4* __restrict__ in,
                                                float4* __restrict__ out, W7 wt) {
    const int dgroups = DIM / DPB;            // 20
    const int nhc = DIM / CHH;                // 16
    int b  = blockIdx.x;
    int hc = b % nhc;                         // fastest: h-halo L2 locality
    int dg = (b / nhc) % dgroups;
    int nc = b / (nhc * dgroups);
    int c  = threadIdx.x % 40;
    int dl = threadIdx.x / 40;
    int d  = dg * DPB + dl;
    int h0 = hc * CHH;
    const int lane = threadIdx.x & 63;

    const float4* sl  = in  + ((size_t)nc * DIM + d) * SL4;
    float4*       osl = out + ((size_t)nc * DIM + d) * SL4;

    const float4 z4 = make_float4(0.f, 0.f, 0.f, 0.f);
    const float3 z3 = make_float3(0.f, 0.f, 0.f);
    const bool cl  = (c >= 1), cr = (c <= 38);
    const bool eL  = (lane == 0) && cl;       // wave-edge: real left load
    const bool eR  = (lane == 63) && cr;      // wave-edge: real right load
    const float w0 = wt.w[0], w1 = wt.w[1], w2 = wt.w[2], w3 = wt.w[3],
                w4 = wt.w[4], w5 = wt.w[5], w6 = wt.w[6];

    // load stage for pipeline step jj (row h0-3+jj), block-uniform guard
    auto ld = [&](int jj, float4& m, float3& l, float3& r) {
        int hh = h0 - 3 + jj;
        m = z4; l = z3; r = z3;
        if ((unsigned)hh < (unsigned)DIM) {
            const float4* p = sl + hh * 40 + c;
            m = p[0];
            if (eL) l = *(const float3*)((const float*)p - 3);
            if (eR) r = *(const float3*)((const float*)p + 4);
        }
    };
    // compute stage: W-blur from resident regs (6 shuffles, no loads)
    auto wcomb = [&](const float4& m, const float3& lv, const float3& rv) -> float4 {
        float ly = __shfl_up(m.y, 1);
        float lz = __shfl_up(m.z, 1);
        float lw = __shfl_up(m.w, 1);
        float rx = __shfl_down(m.x, 1);
        float ry = __shfl_down(m.y, 1);
        float rz = __shfl_down(m.z, 1);
        if (eL) { ly = lv.x; lz = lv.y; lw = lv.z; }
        if (eR) { rx = rv.x; ry = rv.y; rz = rv.z; }
        if (!cl) { ly = 0.f; lz = 0.f; lw = 0.f; }   // w zero-pad
        if (!cr) { rx = 0.f; ry = 0.f; rz = 0.f; }
        float4 o;
        o.x = w0*ly  + w1*lz  + w2*lw  + w3*m.x + w4*m.y + w5*m.z + w6*m.w;
        o.y = w0*lz  + w1*lw  + w2*m.x + w3*m.y + w4*m.z + w5*m.w + w6*rx;
        o.z = w0*lw  + w1*m.x + w2*m.y + w3*m.z + w4*m.w + w5*rx  + w6*ry;
        o.w = w0*m.x + w1*m.y + w2*m.z + w3*m.w + w4*rx  + w5*ry  + w6*rz;
        return o;
    };

    float4 ring[7];
    float4 mC, mN = z4;
    float3 lC, lN = z3, rC, rN = z3;

    ld(0, mC, lC, rC);                        // prime the pipeline
#pragma unroll
    for (int jj = 0; jj < NSTEPH; ++jj) {
        if (jj < NSTEPH - 1) ld(jj + 1, mN, lN, rN);  // prefetch next row
        ring[jj % 7] = wcomb(mC, lC, rC);             // W-blur current row
        if (jj >= 6) {                                // H-blur + store
            float4 o = z4;
#pragma unroll
            for (int j = 0; j < 7; ++j)
                fma4(o, wt.w[j], ring[(jj + 1 + j) % 7]);
            osl[(h0 + jj - 6) * 40 + c] = o;
        }
        mC = mN; lC = lN; rC = rN;
    }
}

// ---- Fallback: direct 343-tap (only if ws too small) ----
__global__ void blur3d_naive(const float* __restrict__ in, float* __restrict__ out,
                             W7 wt, int total) {
    int idx = blockIdx.x * blockDim.x + threadIdx.x;
    if (idx >= total) return;
    int w = idx % DIM;
    int h = (idx / DIM) % DIM;
    int d = (idx / (DIM * DIM)) % DIM;
    const float* base = in + (idx - w - h * DIM - d * DIM * DIM);
    float acc = 0.f;
    for (int a = 0; a < 7; ++a) {
        int dd = d + a - 3;
        if (dd < 0 || dd >= DIM) continue;
        for (int bb = 0; bb < 7; ++bb) {
            int hh = h + bb - 3;
            if (hh < 0 || hh >= DIM) continue;
            float wab = wt.w[a] * wt.w[bb];
            for (int cx = 0; cx < 7; ++cx) {
                int ww = w + cx - 3;
                if (ww < 0 || ww >= DIM) continue;
                acc += wab * wt.w[cx] * base[(dd * DIM + hh) * DIM + ww];
            }
        }
    }
    out[idx] = acc;
}

extern "C" void kernel_launch(void* const* d_in, const int* in_sizes, int n_in,
                              void* d_out, int out_size, void* d_ws, size_t ws_size,
                              hipStream_t stream) {
    const float* x = (const float*)d_in[0];
    float* out = (float*)d_out;
    const int total = out_size;               // 2*2*160^3

    W7 wt;
    double s = 0.0;
    for (int i = 0; i < 7; ++i) {
        double v = exp(-((i - 3) * (i - 3)) / 8.0);
        wt.w[i] = (float)v;
        s += v;
    }
    for (int i = 0; i < 7; ++i) wt.w[i] = (float)(wt.w[i] / s);

    if (ws_size >= (size_t)total * sizeof(float)) {
        float* tmp = (float*)d_ws;
        const int nc = total / (DIM * DIM * DIM);             // 4
        const int gridD = nc * (DIM / CD1) * (SL4 / 256);     // 4*10*25 = 1000
        blur_d<<<gridD, 256, 0, stream>>>(
            (const float4*)x, (float4*)tmp, wt);
        const int gridWH = nc * (DIM / DPB) * (DIM / CHH);    // 4*20*16 = 1280
        blur_wh2<<<gridWH, 320, 0, stream>>>(
            (const float4*)tmp, (float4*)out, wt);
    } else {
        blur3d_naive<<<(total + 255) / 256, 256, 0, stream>>>(x, out, wt, total);
    }
}